// Round 1
// baseline (1033.109 us; speedup 1.0000x reference)
//
#include <hip/hip_runtime.h>
#include <hip/hip_bf16.h>

constexpr int HID = 512;
constexpr int NH  = 8;
constexpr int HD  = 64;
constexpr int NB  = 2;
constexpr int SEQ = 2048;
constexpr int M   = NB * SEQ;        // 4096 token rows
constexpr int NROWS = NB * NH * SEQ; // 32768 attention rows

typedef __attribute__((ext_vector_type(8))) short bf16x8;
typedef __attribute__((ext_vector_type(4))) float f32x4;

__device__ __forceinline__ unsigned short f2bf(float x){
    union { float f; unsigned u; } v; v.f = x;
    return (unsigned short)((v.u + 0x7fffu + ((v.u >> 16) & 1u)) >> 16);
}
__device__ __forceinline__ float bf2f(unsigned short h){
    union { unsigned u; float f; } v; v.u = (unsigned)h << 16;
    return v.f;
}

// ---------- input convert / split (hi+lo bf16 decomposition of fp32) ----------
__global__ void cvt_split(const float* __restrict__ x, unsigned short* __restrict__ hi,
                          unsigned short* __restrict__ lo, int n){
    int i = blockIdx.x * 256 + threadIdx.x;
    if (i >= n) return;
    float f = x[i];
    unsigned short h = f2bf(f);
    hi[i] = h;
    if (lo) lo[i] = f2bf(f - bf2f(h));
}

// ---------- weight transpose (+optional split): wt[n][k] = w[k][n] ----------
__global__ void cvt_w(const float* __restrict__ w, unsigned short* __restrict__ hi,
                      unsigned short* __restrict__ lo){
    __shared__ float t[32][33];
    int n0 = blockIdx.x * 32, k0 = blockIdx.y * 32;
    int tx = threadIdx.x, ty = threadIdx.y;
    for (int r = ty; r < 32; r += 8)
        t[r][tx] = w[(size_t)(k0 + r) * HID + n0 + tx];
    __syncthreads();
    for (int r = ty; r < 32; r += 8){
        float f = t[tx][r];                       // element (k=k0+tx, n=n0+r)
        unsigned short hb = f2bf(f);
        size_t o = (size_t)(n0 + r) * HID + k0 + tx;
        hi[o] = hb;
        if (lo) lo[o] = f2bf(f - bf2f(hb));
    }
}

// ---------- projection GEMM: Y[4096,512] = X @ W + b, MFMA 16x16x32 bf16 ----------
template<int SPLIT, int VOUT>
__global__ __launch_bounds__(256) void proj_gemm(
    const unsigned short* __restrict__ Ahi, const unsigned short* __restrict__ Alo,
    const unsigned short* __restrict__ Bhi, const unsigned short* __restrict__ Blo,
    const float* __restrict__ bias,
    unsigned short* __restrict__ Ohi, unsigned short* __restrict__ Olo)
{
    __shared__ __align__(16) unsigned short As[SPLIT + 1][64][40];
    __shared__ __align__(16) unsigned short Bs[SPLIT + 1][64][40];
    const int m0 = blockIdx.y * 64, n0 = blockIdx.x * 64;
    const int tid = threadIdx.x, w = tid >> 6, lane = tid & 63;
    const int wm = (w >> 1) * 32, wn = (w & 1) * 32;
    const int srow = tid >> 2, sch = (tid & 3) * 8;
    f32x4 acc[2][2] = {};
    for (int k0 = 0; k0 < HID; k0 += 32){
        *(bf16x8*)&As[0][srow][sch] = *(const bf16x8*)(Ahi + (size_t)(m0 + srow) * HID + k0 + sch);
        *(bf16x8*)&Bs[0][srow][sch] = *(const bf16x8*)(Bhi + (size_t)(n0 + srow) * HID + k0 + sch);
        if (SPLIT){
            *(bf16x8*)&As[1][srow][sch] = *(const bf16x8*)(Alo + (size_t)(m0 + srow) * HID + k0 + sch);
            *(bf16x8*)&Bs[1][srow][sch] = *(const bf16x8*)(Blo + (size_t)(n0 + srow) * HID + k0 + sch);
        }
        __syncthreads();
        const int fr = lane & 15, kc = (lane >> 4) * 8;
        #pragma unroll
        for (int fm = 0; fm < 2; fm++)
        #pragma unroll
        for (int fn = 0; fn < 2; fn++){
            bf16x8 aH = *(bf16x8*)&As[0][wm + fm*16 + fr][kc];
            bf16x8 bH = *(bf16x8*)&Bs[0][wn + fn*16 + fr][kc];
            acc[fm][fn] = __builtin_amdgcn_mfma_f32_16x16x32_bf16(aH, bH, acc[fm][fn], 0, 0, 0);
            if (SPLIT){
                bf16x8 aL = *(bf16x8*)&As[1][wm + fm*16 + fr][kc];
                bf16x8 bL = *(bf16x8*)&Bs[1][wn + fn*16 + fr][kc];
                acc[fm][fn] = __builtin_amdgcn_mfma_f32_16x16x32_bf16(aL, bH, acc[fm][fn], 0, 0, 0);
                acc[fm][fn] = __builtin_amdgcn_mfma_f32_16x16x32_bf16(aH, bL, acc[fm][fn], 0, 0, 0);
            }
        }
        __syncthreads();
    }
    #pragma unroll
    for (int fm = 0; fm < 2; fm++)
    #pragma unroll
    for (int fn = 0; fn < 2; fn++){
        int col = n0 + wn + fn*16 + (lane & 15);
        int rb  = m0 + wm + fm*16 + (lane >> 4) * 4;
        float bv = bias[col];
        int h = col >> 6, d = col & 63;
        #pragma unroll
        for (int e = 0; e < 4; e++){
            int m = rb + e;
            int b = m >> 11, s = m & (SEQ - 1);
            float y = acc[fm][fn][e] + bv;
            if (VOUT){
                Ohi[((size_t)((b * NH + h) * HD + d)) * SEQ + s] = f2bf(y);
            } else {
                size_t o = ((size_t)((b * NH + h) * SEQ + s)) * HD + d;
                unsigned short hb = f2bf(y);
                Ohi[o] = hb;
                if (SPLIT) Olo[o] = f2bf(y - bf2f(hb));
            }
        }
    }
}

// ---------- fused attention: sums pass + (recompute, normalize, write, PV) pass ----------
// grid (sqb=32, bh=16), 512 threads = 8 waves (2 sq-halves x 4 sk/d-quarters).
// LDS ~38KB -> 2 blocks/CU (grid-limited), 16 waves/CU with VGPR<=128.
__global__ __launch_bounds__(512, 4) void attn_fused(
    const unsigned short* __restrict__ qh_hi, const unsigned short* __restrict__ qh_lo,
    const unsigned short* __restrict__ kh_hi, const unsigned short* __restrict__ kh_lo,
    const unsigned short* __restrict__ vh_t,
    const float* __restrict__ attn_bias, const int* __restrict__ attn_mask,
    float* __restrict__ scores, unsigned short* __restrict__ ctx)
{
    __shared__ __align__(16) unsigned short Ks[2][64][72];   // K tile hi/lo [sk][d]
    __shared__ __align__(16) unsigned short Vs[64][72];      // V^T tile [d][sk]
    __shared__ __align__(16) unsigned short Ps[64][72];      // P tile bf16 [sq][sk] / ctx stage
    __shared__ float rs[64][4];
    __shared__ float il[64];

    const int sq0 = blockIdx.x * 64;
    const int bh  = blockIdx.y;
    const int b   = bh >> 3, h = bh & 7;
    const int tid = threadIdx.x;
    const int w   = tid >> 6, lane = tid & 63;
    const int wv  = w >> 2;            // sq half (0/1)
    const int wn  = (w & 3) * 16;      // sk (QK) / d (PV) quarter
    const int fr  = lane & 15, lg = lane >> 4;
    const int kc8 = lg * 8;
    const int srow = tid >> 3, sch = (tid & 7) * 8;   // staging assignment

    // Q fragments in registers for the whole block (hi/lo), rows sq0+wv*32+fm*16+fr
    bf16x8 qHf[2][2], qLf[2][2];   // [fm][ks]
    #pragma unroll
    for (int fm = 0; fm < 2; fm++){
        size_t qrow = ((size_t)bh * SEQ + sq0 + wv*32 + fm*16 + fr) * HD;
        #pragma unroll
        for (int ks = 0; ks < 2; ks++){
            qHf[fm][ks] = *(const bf16x8*)(qh_hi + qrow + ks*32 + kc8);
            qLf[fm][ks] = *(const bf16x8*)(qh_lo + qrow + ks*32 + kc8);
        }
    }

    // ---- pass A: row sums of exp(QK/8 + bias, masked) ----
    float rsum[2][4] = {};   // [fm][e], per-lane partial over this lane's columns
    for (int sk0 = 0; sk0 < SEQ; sk0 += 64){
        {
            size_t koff = ((size_t)bh * SEQ + sk0 + srow) * HD + sch;
            *(bf16x8*)&Ks[0][srow][sch] = *(const bf16x8*)(kh_hi + koff);
            *(bf16x8*)&Ks[1][srow][sch] = *(const bf16x8*)(kh_lo + koff);
        }
        __syncthreads();
        f32x4 acc[2] = {};
        #pragma unroll
        for (int ks = 0; ks < 2; ks++){
            bf16x8 bH = *(bf16x8*)&Ks[0][wn + fr][ks*32 + kc8];
            bf16x8 bL = *(bf16x8*)&Ks[1][wn + fr][ks*32 + kc8];
            #pragma unroll
            for (int fm = 0; fm < 2; fm++){
                acc[fm] = __builtin_amdgcn_mfma_f32_16x16x32_bf16(qHf[fm][ks], bH, acc[fm], 0, 0, 0);
                acc[fm] = __builtin_amdgcn_mfma_f32_16x16x32_bf16(qLf[fm][ks], bH, acc[fm], 0, 0, 0);
                acc[fm] = __builtin_amdgcn_mfma_f32_16x16x32_bf16(qHf[fm][ks], bL, acc[fm], 0, 0, 0);
            }
        }
        #pragma unroll
        for (int fm = 0; fm < 2; fm++){
            int row = sq0 + wv*32 + fm*16 + lg*4;
            const float* bp = attn_bias + ((size_t)bh * SEQ + row) * SEQ + sk0 + wn + fr;
            const int*   mp = attn_mask + ((size_t)b  * SEQ + row) * SEQ + sk0 + wn + fr;
            #pragma unroll
            for (int e = 0; e < 4; e++){
                float bv = bp[(size_t)e * SEQ];
                int   mv = mp[(size_t)e * SEQ];
                float p = mv ? 0.f : __expf(acc[fm][e] * 0.125f + bv);
                rsum[fm][e] += p;
            }
        }
        __syncthreads();
    }
    // reduce across the 16-lane column group (rows preserved: lg untouched by xor<16)
    #pragma unroll
    for (int m = 1; m < 16; m <<= 1)
        #pragma unroll
        for (int fm = 0; fm < 2; fm++)
            #pragma unroll
            for (int e = 0; e < 4; e++)
                rsum[fm][e] += __shfl_xor(rsum[fm][e], m, 64);
    if (fr == 0){
        #pragma unroll
        for (int fm = 0; fm < 2; fm++)
            #pragma unroll
            for (int e = 0; e < 4; e++)
                rs[wv*32 + fm*16 + lg*4 + e][w & 3] = rsum[fm][e];
    }
    __syncthreads();
    if (tid < 64) il[tid] = 1.0f / (rs[tid][0] + rs[tid][1] + rs[tid][2] + rs[tid][3]);
    __syncthreads();
    float ilv[2][4];
    #pragma unroll
    for (int fm = 0; fm < 2; fm++)
        #pragma unroll
        for (int e = 0; e < 4; e++)
            ilv[fm][e] = il[wv*32 + fm*16 + lg*4 + e];

    // ---- pass B: recompute, normalize, write scores, fuse P@V ----
    f32x4 cacc[2] = {};
    for (int sk0 = 0; sk0 < SEQ; sk0 += 64){
        {
            size_t koff = ((size_t)bh * SEQ + sk0 + srow) * HD + sch;
            *(bf16x8*)&Ks[0][srow][sch] = *(const bf16x8*)(kh_hi + koff);
            *(bf16x8*)&Ks[1][srow][sch] = *(const bf16x8*)(kh_lo + koff);
            *(bf16x8*)&Vs[srow][sch]    = *(const bf16x8*)(vh_t + ((size_t)bh * HD + srow) * SEQ + sk0 + sch);
        }
        __syncthreads();
        f32x4 acc[2] = {};
        #pragma unroll
        for (int ks = 0; ks < 2; ks++){
            bf16x8 bH = *(bf16x8*)&Ks[0][wn + fr][ks*32 + kc8];
            bf16x8 bL = *(bf16x8*)&Ks[1][wn + fr][ks*32 + kc8];
            #pragma unroll
            for (int fm = 0; fm < 2; fm++){
                acc[fm] = __builtin_amdgcn_mfma_f32_16x16x32_bf16(qHf[fm][ks], bH, acc[fm], 0, 0, 0);
                acc[fm] = __builtin_amdgcn_mfma_f32_16x16x32_bf16(qLf[fm][ks], bH, acc[fm], 0, 0, 0);
                acc[fm] = __builtin_amdgcn_mfma_f32_16x16x32_bf16(qHf[fm][ks], bL, acc[fm], 0, 0, 0);
            }
        }
        #pragma unroll
        for (int fm = 0; fm < 2; fm++){
            int row = sq0 + wv*32 + fm*16 + lg*4;
            const float* bp = attn_bias + ((size_t)bh * SEQ + row) * SEQ + sk0 + wn + fr;
            const int*   mp = attn_mask + ((size_t)b  * SEQ + row) * SEQ + sk0 + wn + fr;
            float*       sp = scores    + ((size_t)bh * SEQ + row) * SEQ + sk0 + wn + fr;
            #pragma unroll
            for (int e = 0; e < 4; e++){
                float bv = bp[(size_t)e * SEQ];
                int   mv = mp[(size_t)e * SEQ];
                float p = mv ? 0.f : __expf(acc[fm][e] * 0.125f + bv);
                float pn = p * ilv[fm][e];
                sp[(size_t)e * SEQ] = pn;                               // final scores (only write)
                Ps[wv*32 + fm*16 + lg*4 + e][wn + fr] = f2bf(pn);
            }
        }
        __syncthreads();
        #pragma unroll
        for (int ks = 0; ks < 2; ks++){
            bf16x8 bV = *(bf16x8*)&Vs[wn + fr][ks*32 + kc8];
            #pragma unroll
            for (int fm = 0; fm < 2; fm++){
                bf16x8 a = *(bf16x8*)&Ps[wv*32 + fm*16 + fr][ks*32 + kc8];
                cacc[fm] = __builtin_amdgcn_mfma_f32_16x16x32_bf16(a, bV, cacc[fm], 0, 0, 0);
            }
        }
        __syncthreads();
    }
    // ctx epilogue: stage bf16 ctx tile in Ps, vector-store to [b,s,h*64+d]
    #pragma unroll
    for (int fm = 0; fm < 2; fm++)
        #pragma unroll
        for (int e = 0; e < 4; e++)
            Ps[wv*32 + fm*16 + lg*4 + e][wn + fr] = f2bf(cacc[fm][e]);
    __syncthreads();
    {
        bf16x8 v = *(bf16x8*)&Ps[srow][sch];
        *(bf16x8*)(ctx + ((size_t)(b * SEQ + sq0 + srow)) * HID + h * HD + sch) = v;
    }
}

// ---------- out = ctx @ Wo + bo (fp32 out) ----------
__global__ __launch_bounds__(256) void out_gemm(
    const unsigned short* __restrict__ A, const unsigned short* __restrict__ Bt,
    const float* __restrict__ bias, float* __restrict__ out)
{
    __shared__ __align__(16) unsigned short As[64][40];
    __shared__ __align__(16) unsigned short Bs[64][40];
    const int m0 = blockIdx.y * 64, n0 = blockIdx.x * 64;
    const int tid = threadIdx.x, w = tid >> 6, lane = tid & 63;
    const int wm = (w >> 1) * 32, wn = (w & 1) * 32;
    const int srow = tid >> 2, sch = (tid & 3) * 8;
    f32x4 acc[2][2] = {};
    for (int k0 = 0; k0 < HID; k0 += 32){
        *(bf16x8*)&As[srow][sch] = *(const bf16x8*)(A  + (size_t)(m0 + srow) * HID + k0 + sch);
        *(bf16x8*)&Bs[srow][sch] = *(const bf16x8*)(Bt + (size_t)(n0 + srow) * HID + k0 + sch);
        __syncthreads();
        const int fr = lane & 15, kc = (lane >> 4) * 8;
        #pragma unroll
        for (int fm = 0; fm < 2; fm++)
        #pragma unroll
        for (int fn = 0; fn < 2; fn++){
            bf16x8 a = *(bf16x8*)&As[wm + fm*16 + fr][kc];
            bf16x8 b = *(bf16x8*)&Bs[wn + fn*16 + fr][kc];
            acc[fm][fn] = __builtin_amdgcn_mfma_f32_16x16x32_bf16(a, b, acc[fm][fn], 0, 0, 0);
        }
        __syncthreads();
    }
    #pragma unroll
    for (int fm = 0; fm < 2; fm++)
    #pragma unroll
    for (int fn = 0; fn < 2; fn++){
        int col = n0 + wn + fn*16 + (lane & 15);
        int rb  = m0 + wm + fm*16 + (lane >> 4) * 4;
        float bv = bias[col];
        #pragma unroll
        for (int e = 0; e < 4; e++)
            out[(size_t)(rb + e) * HID + col] = acc[fm][fn][e] + bv;
    }
}

extern "C" void kernel_launch(void* const* d_in, const int* in_sizes, int n_in,
                              void* d_out, int out_size, void* d_ws, size_t ws_size,
                              hipStream_t stream)
{
    const float* q  = (const float*)d_in[0];
    const float* k  = (const float*)d_in[1];
    const float* v  = (const float*)d_in[2];
    const float* attn_bias = (const float*)d_in[3];
    const int*   attn_mask = (const int*)d_in[4];
    const float* Wq = (const float*)d_in[5];
    const float* bq = (const float*)d_in[6];
    const float* Wk = (const float*)d_in[7];
    const float* bk = (const float*)d_in[8];
    const float* Wv = (const float*)d_in[9];
    const float* bv = (const float*)d_in[10];
    const float* Wo = (const float*)d_in[11];
    const float* bo = (const float*)d_in[12];

    float* out = (float*)d_out;
    float* scores = out + (size_t)M * HID;   // final normalized scores output

    char* p = (char*)d_ws;
    auto alloc = [&](size_t bytes){ char* r = p; p += (bytes + 255) & ~(size_t)255; return r; };
    const size_t PLANE  = (size_t)M * HID * 2;     // 4 MB bf16 plane
    const size_t WPLANE = (size_t)HID * HID * 2;   // 0.5 MB
    unsigned short* q_hi = (unsigned short*)alloc(PLANE);
    unsigned short* q_lo = (unsigned short*)alloc(PLANE);
    unsigned short* k_hi = (unsigned short*)alloc(PLANE);
    unsigned short* k_lo = (unsigned short*)alloc(PLANE);
    unsigned short* v_b  = (unsigned short*)alloc(PLANE);
    unsigned short* wqt_hi = (unsigned short*)alloc(WPLANE);
    unsigned short* wqt_lo = (unsigned short*)alloc(WPLANE);
    unsigned short* wkt_hi = (unsigned short*)alloc(WPLANE);
    unsigned short* wkt_lo = (unsigned short*)alloc(WPLANE);
    unsigned short* wvt    = (unsigned short*)alloc(WPLANE);
    unsigned short* wot    = (unsigned short*)alloc(WPLANE);
    unsigned short* qh_hi = (unsigned short*)alloc(PLANE);
    unsigned short* qh_lo = (unsigned short*)alloc(PLANE);
    unsigned short* kh_hi = (unsigned short*)alloc(PLANE);
    unsigned short* kh_lo = (unsigned short*)alloc(PLANE);
    unsigned short* vh_t  = (unsigned short*)alloc(PLANE);
    unsigned short* ctx   = (unsigned short*)alloc(PLANE);
    if ((size_t)(p - (char*)d_ws) > ws_size) return;

    const int n = M * HID;
    cvt_split<<<(n + 255) / 256, 256, 0, stream>>>(q, q_hi, q_lo, n);
    cvt_split<<<(n + 255) / 256, 256, 0, stream>>>(k, k_hi, k_lo, n);
    cvt_split<<<(n + 255) / 256, 256, 0, stream>>>(v, v_b, nullptr, n);
    dim3 wb(32, 8);
    cvt_w<<<dim3(16, 16), wb, 0, stream>>>(Wq, wqt_hi, wqt_lo);
    cvt_w<<<dim3(16, 16), wb, 0, stream>>>(Wk, wkt_hi, wkt_lo);
    cvt_w<<<dim3(16, 16), wb, 0, stream>>>(Wv, wvt, nullptr);
    cvt_w<<<dim3(16, 16), wb, 0, stream>>>(Wo, wot, nullptr);

    dim3 pg(HID / 64, M / 64);
    proj_gemm<1,0><<<pg, 256, 0, stream>>>(q_hi, q_lo, wqt_hi, wqt_lo, bq, qh_hi, qh_lo);
    proj_gemm<1,0><<<pg, 256, 0, stream>>>(k_hi, k_lo, wkt_hi, wkt_lo, bk, kh_hi, kh_lo);
    proj_gemm<0,1><<<pg, 256, 0, stream>>>(v_b, nullptr, wvt, nullptr, bv, vh_t, nullptr);

    attn_fused<<<dim3(SEQ / 64, NB * NH), 512, 0, stream>>>(
        qh_hi, qh_lo, kh_hi, kh_lo, vh_t, attn_bias, attn_mask, scores, ctx);

    out_gemm<<<dim3(HID / 64, M / 64), 256, 0, stream>>>(ctx, wot, bo, out);
}

// Round 2
// 717.958 us; speedup vs baseline: 1.4390x; 1.4390x over previous
//
#include <hip/hip_runtime.h>
#include <hip/hip_bf16.h>

constexpr int HID = 512;
constexpr int NH  = 8;
constexpr int HD  = 64;
constexpr int NB  = 2;
constexpr int SEQ = 2048;
constexpr int M   = NB * SEQ;        // 4096 token rows
constexpr int NROWS = NB * NH * SEQ; // 32768 attention rows

typedef __attribute__((ext_vector_type(8))) short bf16x8;
typedef __attribute__((ext_vector_type(4))) float f32x4;

__device__ __forceinline__ unsigned short f2bf(float x){
    union { float f; unsigned u; } v; v.f = x;
    return (unsigned short)((v.u + 0x7fffu + ((v.u >> 16) & 1u)) >> 16);
}
__device__ __forceinline__ float bf2f(unsigned short h){
    union { unsigned u; float f; } v; v.u = (unsigned)h << 16;
    return v.f;
}

// ---------- input convert / split (hi+lo bf16 decomposition of fp32) ----------
__global__ void cvt_split(const float* __restrict__ x, unsigned short* __restrict__ hi,
                          unsigned short* __restrict__ lo, int n){
    int i = blockIdx.x * 256 + threadIdx.x;
    if (i >= n) return;
    float f = x[i];
    unsigned short h = f2bf(f);
    hi[i] = h;
    if (lo) lo[i] = f2bf(f - bf2f(h));
}

// ---------- weight transpose (+optional split): wt[n][k] = w[k][n] ----------
__global__ void cvt_w(const float* __restrict__ w, unsigned short* __restrict__ hi,
                      unsigned short* __restrict__ lo){
    __shared__ float t[32][33];
    int n0 = blockIdx.x * 32, k0 = blockIdx.y * 32;
    int tx = threadIdx.x, ty = threadIdx.y;
    for (int r = ty; r < 32; r += 8)
        t[r][tx] = w[(size_t)(k0 + r) * HID + n0 + tx];
    __syncthreads();
    for (int r = ty; r < 32; r += 8){
        float f = t[tx][r];                       // element (k=k0+tx, n=n0+r)
        unsigned short hb = f2bf(f);
        size_t o = (size_t)(n0 + r) * HID + k0 + tx;
        hi[o] = hb;
        if (lo) lo[o] = f2bf(f - bf2f(hb));
    }
}

// ---------- projection GEMM: Y[4096,512] = X @ W + b, MFMA 16x16x32 bf16 ----------
template<int SPLIT, int VOUT>
__global__ __launch_bounds__(256) void proj_gemm(
    const unsigned short* __restrict__ Ahi, const unsigned short* __restrict__ Alo,
    const unsigned short* __restrict__ Bhi, const unsigned short* __restrict__ Blo,
    const float* __restrict__ bias,
    unsigned short* __restrict__ Ohi, unsigned short* __restrict__ Olo)
{
    __shared__ __align__(16) unsigned short As[SPLIT + 1][64][40];
    __shared__ __align__(16) unsigned short Bs[SPLIT + 1][64][40];
    const int m0 = blockIdx.y * 64, n0 = blockIdx.x * 64;
    const int tid = threadIdx.x, w = tid >> 6, lane = tid & 63;
    const int wm = (w >> 1) * 32, wn = (w & 1) * 32;
    const int srow = tid >> 2, sch = (tid & 3) * 8;
    f32x4 acc[2][2] = {};
    for (int k0 = 0; k0 < HID; k0 += 32){
        *(bf16x8*)&As[0][srow][sch] = *(const bf16x8*)(Ahi + (size_t)(m0 + srow) * HID + k0 + sch);
        *(bf16x8*)&Bs[0][srow][sch] = *(const bf16x8*)(Bhi + (size_t)(n0 + srow) * HID + k0 + sch);
        if (SPLIT){
            *(bf16x8*)&As[1][srow][sch] = *(const bf16x8*)(Alo + (size_t)(m0 + srow) * HID + k0 + sch);
            *(bf16x8*)&Bs[1][srow][sch] = *(const bf16x8*)(Blo + (size_t)(n0 + srow) * HID + k0 + sch);
        }
        __syncthreads();
        const int fr = lane & 15, kc = (lane >> 4) * 8;
        #pragma unroll
        for (int fm = 0; fm < 2; fm++)
        #pragma unroll
        for (int fn = 0; fn < 2; fn++){
            bf16x8 aH = *(bf16x8*)&As[0][wm + fm*16 + fr][kc];
            bf16x8 bH = *(bf16x8*)&Bs[0][wn + fn*16 + fr][kc];
            acc[fm][fn] = __builtin_amdgcn_mfma_f32_16x16x32_bf16(aH, bH, acc[fm][fn], 0, 0, 0);
            if (SPLIT){
                bf16x8 aL = *(bf16x8*)&As[1][wm + fm*16 + fr][kc];
                bf16x8 bL = *(bf16x8*)&Bs[1][wn + fn*16 + fr][kc];
                acc[fm][fn] = __builtin_amdgcn_mfma_f32_16x16x32_bf16(aL, bH, acc[fm][fn], 0, 0, 0);
                acc[fm][fn] = __builtin_amdgcn_mfma_f32_16x16x32_bf16(aH, bL, acc[fm][fn], 0, 0, 0);
            }
        }
        __syncthreads();
    }
    #pragma unroll
    for (int fm = 0; fm < 2; fm++)
    #pragma unroll
    for (int fn = 0; fn < 2; fn++){
        int col = n0 + wn + fn*16 + (lane & 15);
        int rb  = m0 + wm + fm*16 + (lane >> 4) * 4;
        float bv = bias[col];
        int h = col >> 6, d = col & 63;
        #pragma unroll
        for (int e = 0; e < 4; e++){
            int m = rb + e;
            int b = m >> 11, s = m & (SEQ - 1);
            float y = acc[fm][fn][e] + bv;
            if (VOUT){
                Ohi[((size_t)((b * NH + h) * HD + d)) * SEQ + s] = f2bf(y);
            } else {
                size_t o = ((size_t)((b * NH + h) * SEQ + s)) * HD + d;
                unsigned short hb = f2bf(y);
                Ohi[o] = hb;
                if (SPLIT) Olo[o] = f2bf(y - bf2f(hb));
            }
        }
    }
}

// ---------- fused attention: sum pass + (recompute, normalize, write, PV) pass ----------
// Swapped QK mfma (A=K, B=Q) -> acc elements = 4 consecutive sk of one sq row:
// bias/mask/scores go float4/int4. One-step register prefetch of K/V tiles and
// bias/mask hides HBM latency under the MFMA+exp phases.
__global__ __launch_bounds__(512, 4) void attn_fused(
    const unsigned short* __restrict__ qh_hi, const unsigned short* __restrict__ qh_lo,
    const unsigned short* __restrict__ kh_hi, const unsigned short* __restrict__ kh_lo,
    const unsigned short* __restrict__ vh_t,
    const float* __restrict__ attn_bias, const int* __restrict__ attn_mask,
    float* __restrict__ scores, unsigned short* __restrict__ ctx)
{
    __shared__ __align__(16) unsigned short Ks[2][64][72];   // K tile hi/lo [sk][d]
    __shared__ __align__(16) unsigned short Vs[64][72];      // V^T tile [d][sk]
    __shared__ __align__(16) unsigned short Ps[64][72];      // P tile bf16 [sq][sk] / ctx stage
    __shared__ float rs[64][4];
    __shared__ float il[64];

    const int sq0 = blockIdx.x * 64;
    const int bh  = blockIdx.y;
    const int b   = bh >> 3, h = bh & 7;
    const int tid = threadIdx.x;
    const int w   = tid >> 6, lane = tid & 63;
    const int wv  = w >> 2;            // sq half (0/1)
    const int q4  = w & 3;             // sk (QK) / d (PV) quarter
    const int fr  = lane & 15, lg = lane >> 4;
    const int kc8 = lg * 8;
    const int skw = q4 * 16;
    const int srow = tid >> 3, sch = (tid & 7) * 8;   // staging assignment

    // Q fragments in registers for the whole block (hi/lo), rows sq0+wv*32+fm*16+fr
    bf16x8 qHf[2][2], qLf[2][2];   // [fm][ks]
    #pragma unroll
    for (int fm = 0; fm < 2; fm++){
        size_t qrow = ((size_t)bh * SEQ + sq0 + wv*32 + fm*16 + fr) * HD;
        #pragma unroll
        for (int ks = 0; ks < 2; ks++){
            qHf[fm][ks] = *(const bf16x8*)(qh_hi + qrow + ks*32 + kc8);
            qLf[fm][ks] = *(const bf16x8*)(qh_lo + qrow + ks*32 + kc8);
        }
    }

    // per-thread bias/mask/scores element offsets (sk0 added per step)
    size_t boff[2], moff[2];
    #pragma unroll
    for (int fm = 0; fm < 2; fm++){
        int sq = sq0 + wv*32 + fm*16 + fr;
        boff[fm] = ((size_t)bh * SEQ + sq) * SEQ + skw + lg*4;
        moff[fm] = ((size_t)b  * SEQ + sq) * SEQ + skw + lg*4;
    }
    const size_t kbase = (size_t)bh * SEQ * HD;

    // ---- prologue prefetch: K tile 0, bias/mask tile 0 ----
    bf16x8 kHr, kLr;
    {
        size_t ko = kbase + (size_t)srow * HD + sch;
        kHr = *(const bf16x8*)(kh_hi + ko);
        kLr = *(const bf16x8*)(kh_lo + ko);
    }
    float4 bR[2]; int4 mR[2];
    #pragma unroll
    for (int fm = 0; fm < 2; fm++){
        bR[fm] = *(const float4*)(attn_bias + boff[fm]);
        mR[fm] = *(const int4*)(attn_mask + moff[fm]);
    }

    // ---- pass A: row sums of exp(QK/8 + bias, masked) ----
    float rsum[2] = {0.f, 0.f};
    for (int sk0 = 0; sk0 < SEQ; sk0 += 64){
        *(bf16x8*)&Ks[0][srow][sch] = kHr;
        *(bf16x8*)&Ks[1][srow][sch] = kLr;
        {   // prefetch next K tile (wraps to 0 on last iter; reused by pass B)
            int skn = (sk0 + 64) & (SEQ - 1);
            size_t ko = kbase + (size_t)(skn + srow) * HD + sch;
            kHr = *(const bf16x8*)(kh_hi + ko);
            kLr = *(const bf16x8*)(kh_lo + ko);
        }
        __syncthreads();
        f32x4 acc[2] = {};
        #pragma unroll
        for (int ks = 0; ks < 2; ks++){
            bf16x8 kH = *(bf16x8*)&Ks[0][skw + fr][ks*32 + kc8];
            bf16x8 kL = *(bf16x8*)&Ks[1][skw + fr][ks*32 + kc8];
            #pragma unroll
            for (int fm = 0; fm < 2; fm++){
                acc[fm] = __builtin_amdgcn_mfma_f32_16x16x32_bf16(kH, qHf[fm][ks], acc[fm], 0, 0, 0);
                acc[fm] = __builtin_amdgcn_mfma_f32_16x16x32_bf16(kH, qLf[fm][ks], acc[fm], 0, 0, 0);
                acc[fm] = __builtin_amdgcn_mfma_f32_16x16x32_bf16(kL, qHf[fm][ks], acc[fm], 0, 0, 0);
            }
        }
        #pragma unroll
        for (int fm = 0; fm < 2; fm++){
            float4 bv = bR[fm]; int4 mv = mR[fm];
            float p0 = mv.x ? 0.f : __expf(acc[fm][0] * 0.125f + bv.x);
            float p1 = mv.y ? 0.f : __expf(acc[fm][1] * 0.125f + bv.y);
            float p2 = mv.z ? 0.f : __expf(acc[fm][2] * 0.125f + bv.z);
            float p3 = mv.w ? 0.f : __expf(acc[fm][3] * 0.125f + bv.w);
            rsum[fm] += (p0 + p1) + (p2 + p3);
        }
        {   // prefetch next bias/mask (wraps; reused by pass B)
            int skn = (sk0 + 64) & (SEQ - 1);
            #pragma unroll
            for (int fm = 0; fm < 2; fm++){
                bR[fm] = *(const float4*)(attn_bias + boff[fm] + skn);
                mR[fm] = *(const int4*)(attn_mask + moff[fm] + skn);
            }
        }
        __syncthreads();
    }
    // reduce over the 4 lane-groups (rows preserved: fr untouched by xor 16/32)
    #pragma unroll
    for (int fm = 0; fm < 2; fm++){
        rsum[fm] += __shfl_xor(rsum[fm], 16, 64);
        rsum[fm] += __shfl_xor(rsum[fm], 32, 64);
    }
    if (lg == 0){
        #pragma unroll
        for (int fm = 0; fm < 2; fm++)
            rs[wv*32 + fm*16 + fr][q4] = rsum[fm];
    }
    __syncthreads();
    if (tid < 64) il[tid] = 1.0f / (rs[tid][0] + rs[tid][1] + rs[tid][2] + rs[tid][3]);
    __syncthreads();
    float ilv[2];
    #pragma unroll
    for (int fm = 0; fm < 2; fm++)
        ilv[fm] = il[wv*32 + fm*16 + fr];

    // ---- pass B: recompute, normalize, write scores, fuse P@V ----
    // kHr/kLr and bR/mR already hold tile 0 (wrapped prefetch from pass A).
    bf16x8 vRr;
    vRr = *(const bf16x8*)(vh_t + ((size_t)bh * HD + srow) * SEQ + sch);
    f32x4 cacc[2] = {};
    for (int sk0 = 0; sk0 < SEQ; sk0 += 64){
        *(bf16x8*)&Ks[0][srow][sch] = kHr;
        *(bf16x8*)&Ks[1][srow][sch] = kLr;
        *(bf16x8*)&Vs[srow][sch]    = vRr;
        {   // prefetch next K/V tile
            int skn = (sk0 + 64) & (SEQ - 1);
            size_t ko = kbase + (size_t)(skn + srow) * HD + sch;
            kHr = *(const bf16x8*)(kh_hi + ko);
            kLr = *(const bf16x8*)(kh_lo + ko);
            vRr = *(const bf16x8*)(vh_t + ((size_t)bh * HD + srow) * SEQ + skn + sch);
        }
        __syncthreads();
        f32x4 acc[2] = {};
        #pragma unroll
        for (int ks = 0; ks < 2; ks++){
            bf16x8 kH = *(bf16x8*)&Ks[0][skw + fr][ks*32 + kc8];
            bf16x8 kL = *(bf16x8*)&Ks[1][skw + fr][ks*32 + kc8];
            #pragma unroll
            for (int fm = 0; fm < 2; fm++){
                acc[fm] = __builtin_amdgcn_mfma_f32_16x16x32_bf16(kH, qHf[fm][ks], acc[fm], 0, 0, 0);
                acc[fm] = __builtin_amdgcn_mfma_f32_16x16x32_bf16(kH, qLf[fm][ks], acc[fm], 0, 0, 0);
                acc[fm] = __builtin_amdgcn_mfma_f32_16x16x32_bf16(kL, qHf[fm][ks], acc[fm], 0, 0, 0);
            }
        }
        #pragma unroll
        for (int fm = 0; fm < 2; fm++){
            float4 bv = bR[fm]; int4 mv = mR[fm];
            float pn0 = (mv.x ? 0.f : __expf(acc[fm][0] * 0.125f + bv.x)) * ilv[fm];
            float pn1 = (mv.y ? 0.f : __expf(acc[fm][1] * 0.125f + bv.y)) * ilv[fm];
            float pn2 = (mv.z ? 0.f : __expf(acc[fm][2] * 0.125f + bv.z)) * ilv[fm];
            float pn3 = (mv.w ? 0.f : __expf(acc[fm][3] * 0.125f + bv.w)) * ilv[fm];
            float4 pnv; pnv.x = pn0; pnv.y = pn1; pnv.z = pn2; pnv.w = pn3;
            *(float4*)(scores + boff[fm] + sk0) = pnv;          // final scores (only write)
            ushort4 us; us.x = f2bf(pn0); us.y = f2bf(pn1); us.z = f2bf(pn2); us.w = f2bf(pn3);
            *(ushort4*)&Ps[wv*32 + fm*16 + fr][skw + lg*4] = us;
        }
        {   // prefetch next bias/mask
            int skn = (sk0 + 64) & (SEQ - 1);
            #pragma unroll
            for (int fm = 0; fm < 2; fm++){
                bR[fm] = *(const float4*)(attn_bias + boff[fm] + skn);
                mR[fm] = *(const int4*)(attn_mask + moff[fm] + skn);
            }
        }
        __syncthreads();
        #pragma unroll
        for (int ks = 0; ks < 2; ks++){
            bf16x8 bV = *(bf16x8*)&Vs[skw + fr][ks*32 + kc8];
            #pragma unroll
            for (int fm = 0; fm < 2; fm++){
                bf16x8 a = *(bf16x8*)&Ps[wv*32 + fm*16 + fr][ks*32 + kc8];
                cacc[fm] = __builtin_amdgcn_mfma_f32_16x16x32_bf16(a, bV, cacc[fm], 0, 0, 0);
            }
        }
        __syncthreads();
    }
    // ctx epilogue: stage bf16 ctx tile in Ps, vector-store to [b,s,h*64+d]
    #pragma unroll
    for (int fm = 0; fm < 2; fm++)
        #pragma unroll
        for (int e = 0; e < 4; e++)
            Ps[wv*32 + fm*16 + lg*4 + e][skw + fr] = f2bf(cacc[fm][e]);
    __syncthreads();
    {
        bf16x8 v = *(bf16x8*)&Ps[srow][sch];
        *(bf16x8*)(ctx + ((size_t)(b * SEQ + sq0 + srow)) * HID + h * HD + sch) = v;
    }
}

// ---------- out = ctx @ Wo + bo (fp32 out) ----------
__global__ __launch_bounds__(256) void out_gemm(
    const unsigned short* __restrict__ A, const unsigned short* __restrict__ Bt,
    const float* __restrict__ bias, float* __restrict__ out)
{
    __shared__ __align__(16) unsigned short As[64][40];
    __shared__ __align__(16) unsigned short Bs[64][40];
    const int m0 = blockIdx.y * 64, n0 = blockIdx.x * 64;
    const int tid = threadIdx.x, w = tid >> 6, lane = tid & 63;
    const int wm = (w >> 1) * 32, wn = (w & 1) * 32;
    const int srow = tid >> 2, sch = (tid & 3) * 8;
    f32x4 acc[2][2] = {};
    for (int k0 = 0; k0 < HID; k0 += 32){
        *(bf16x8*)&As[srow][sch] = *(const bf16x8*)(A  + (size_t)(m0 + srow) * HID + k0 + sch);
        *(bf16x8*)&Bs[srow][sch] = *(const bf16x8*)(Bt + (size_t)(n0 + srow) * HID + k0 + sch);
        __syncthreads();
        const int fr = lane & 15, kc = (lane >> 4) * 8;
        #pragma unroll
        for (int fm = 0; fm < 2; fm++)
        #pragma unroll
        for (int fn = 0; fn < 2; fn++){
            bf16x8 a = *(bf16x8*)&As[wm + fm*16 + fr][kc];
            bf16x8 b = *(bf16x8*)&Bs[wn + fn*16 + fr][kc];
            acc[fm][fn] = __builtin_amdgcn_mfma_f32_16x16x32_bf16(a, b, acc[fm][fn], 0, 0, 0);
        }
        __syncthreads();
    }
    #pragma unroll
    for (int fm = 0; fm < 2; fm++)
    #pragma unroll
    for (int fn = 0; fn < 2; fn++){
        int col = n0 + wn + fn*16 + (lane & 15);
        int rb  = m0 + wm + fm*16 + (lane >> 4) * 4;
        float bv = bias[col];
        #pragma unroll
        for (int e = 0; e < 4; e++)
            out[(size_t)(rb + e) * HID + col] = acc[fm][fn][e] + bv;
    }
}

extern "C" void kernel_launch(void* const* d_in, const int* in_sizes, int n_in,
                              void* d_out, int out_size, void* d_ws, size_t ws_size,
                              hipStream_t stream)
{
    const float* q  = (const float*)d_in[0];
    const float* k  = (const float*)d_in[1];
    const float* v  = (const float*)d_in[2];
    const float* attn_bias = (const float*)d_in[3];
    const int*   attn_mask = (const int*)d_in[4];
    const float* Wq = (const float*)d_in[5];
    const float* bq = (const float*)d_in[6];
    const float* Wk = (const float*)d_in[7];
    const float* bk = (const float*)d_in[8];
    const float* Wv = (const float*)d_in[9];
    const float* bv = (const float*)d_in[10];
    const float* Wo = (const float*)d_in[11];
    const float* bo = (const float*)d_in[12];

    float* out = (float*)d_out;
    float* scores = out + (size_t)M * HID;   // final normalized scores output

    char* p = (char*)d_ws;
    auto alloc = [&](size_t bytes){ char* r = p; p += (bytes + 255) & ~(size_t)255; return r; };
    const size_t PLANE  = (size_t)M * HID * 2;     // 4 MB bf16 plane
    const size_t WPLANE = (size_t)HID * HID * 2;   // 0.5 MB
    unsigned short* q_hi = (unsigned short*)alloc(PLANE);
    unsigned short* q_lo = (unsigned short*)alloc(PLANE);
    unsigned short* k_hi = (unsigned short*)alloc(PLANE);
    unsigned short* k_lo = (unsigned short*)alloc(PLANE);
    unsigned short* v_b  = (unsigned short*)alloc(PLANE);
    unsigned short* wqt_hi = (unsigned short*)alloc(WPLANE);
    unsigned short* wqt_lo = (unsigned short*)alloc(WPLANE);
    unsigned short* wkt_hi = (unsigned short*)alloc(WPLANE);
    unsigned short* wkt_lo = (unsigned short*)alloc(WPLANE);
    unsigned short* wvt    = (unsigned short*)alloc(WPLANE);
    unsigned short* wot    = (unsigned short*)alloc(WPLANE);
    unsigned short* qh_hi = (unsigned short*)alloc(PLANE);
    unsigned short* qh_lo = (unsigned short*)alloc(PLANE);
    unsigned short* kh_hi = (unsigned short*)alloc(PLANE);
    unsigned short* kh_lo = (unsigned short*)alloc(PLANE);
    unsigned short* vh_t  = (unsigned short*)alloc(PLANE);
    unsigned short* ctx   = (unsigned short*)alloc(PLANE);
    if ((size_t)(p - (char*)d_ws) > ws_size) return;

    const int n = M * HID;
    cvt_split<<<(n + 255) / 256, 256, 0, stream>>>(q, q_hi, q_lo, n);
    cvt_split<<<(n + 255) / 256, 256, 0, stream>>>(k, k_hi, k_lo, n);
    cvt_split<<<(n + 255) / 256, 256, 0, stream>>>(v, v_b, nullptr, n);
    dim3 wb(32, 8);
    cvt_w<<<dim3(16, 16), wb, 0, stream>>>(Wq, wqt_hi, wqt_lo);
    cvt_w<<<dim3(16, 16), wb, 0, stream>>>(Wk, wkt_hi, wkt_lo);
    cvt_w<<<dim3(16, 16), wb, 0, stream>>>(Wv, wvt, nullptr);
    cvt_w<<<dim3(16, 16), wb, 0, stream>>>(Wo, wot, nullptr);

    dim3 pg(HID / 64, M / 64);
    proj_gemm<1,0><<<pg, 256, 0, stream>>>(q_hi, q_lo, wqt_hi, wqt_lo, bq, qh_hi, qh_lo);
    proj_gemm<1,0><<<pg, 256, 0, stream>>>(k_hi, k_lo, wkt_hi, wkt_lo, bk, kh_hi, kh_lo);
    proj_gemm<0,1><<<pg, 256, 0, stream>>>(v_b, nullptr, wvt, nullptr, bv, vh_t, nullptr);

    attn_fused<<<dim3(SEQ / 64, NB * NH), 512, 0, stream>>>(
        qh_hi, qh_lo, kh_hi, kh_lo, vh_t, attn_bias, attn_mask, scores, ctx);

    out_gemm<<<dim3(HID / 64, M / 64), 256, 0, stream>>>(ctx, wot, bo, out);
}